// Round 9
// baseline (448.782 us; speedup 1.0000x reference)
//
#include <hip/hip_runtime.h>
#include <hip/hip_bf16.h>

#define M_ROWS 16384
#define N_CODES 8192
#define DDIM    512
#define NCHUNK  512          // 16-code chunks per row
#define MARGIN  1.5f         // coarse-vs-exact margin. Coarse bf16-GEMM error
                             // std ~0.125 abs (2*sqrt(1024)*2^-9); threshold
                             // needs eps1+eps2 (std ~0.18); 1.5 = 8 sigma ->
                             // P(miss) ~1e-17/row. (4.0 was ~30 sigma.)

typedef unsigned int u32;
typedef unsigned long long u64;
typedef unsigned short u16;
typedef __attribute__((ext_vector_type(8))) short short8;   // 8 bf16 = 4 VGPRs
typedef __attribute__((ext_vector_type(4))) float f32x4;

__device__ __forceinline__ u32 float_to_ordered(float f) {
    u32 u = __float_as_uint(f);
    return (u & 0x80000000u) ? ~u : (u | 0x80000000u);
}

__device__ __forceinline__ u16 bf16_rne(float x) {
    u32 u = __float_as_uint(x);
    u32 r = u + 0x7FFFu + ((u >> 16) & 1u);
    return (u16)(r >> 16);
}

__device__ __forceinline__ void gl_lds16(const void* g, void* l) {
    __builtin_amdgcn_global_load_lds((const __attribute__((address_space(1))) u32*)g,
                                     (__attribute__((address_space(3))) u32*)l,
                                     16, 0, 0);
}

__device__ __forceinline__ u64 umin64(u64 a, u64 b) { return a < b ? a : b; }

// DPP lane-permute within quads (VALU pipe, avoids ds_bpermute).
// 0xB1 = quad_perm [1,0,3,2] = xor 1;  0x4E = quad_perm [2,3,0,1] = xor 2.
#if __has_builtin(__builtin_amdgcn_update_dpp)
template <int CTRL>
__device__ __forceinline__ float dpp_mov(float x) {
    return __int_as_float(__builtin_amdgcn_update_dpp(
        __float_as_int(x), __float_as_int(x), CTRL, 0xF, 0xF, true));
}
#else
template <int CTRL>
__device__ __forceinline__ float dpp_mov(float x) {
    return __shfl_xor(x, CTRL == 0xB1 ? 1 : 2, 64);
}
#endif

// ---------------------------------------------------------------------------
// Kernel 1: prep (R4-exact).
// ---------------------------------------------------------------------------
__global__ __launch_bounds__(256) void vq_prep(
    const float4* __restrict__ z4, ushort4* __restrict__ zh,
    const float* __restrict__ emb, ushort4* __restrict__ eh,
    float* __restrict__ e_norms) {
    int b = blockIdx.x;
    if (b < (M_ROWS * DDIM) / 1024) {
        int i = b * 256 + threadIdx.x;
        float4 v = z4[i];
        ushort4 h;
        h.x = bf16_rne(v.x); h.y = bf16_rne(v.y);
        h.z = bf16_rne(v.z); h.w = bf16_rne(v.w);
        zh[i] = h;
    } else {
        int wave = threadIdx.x >> 6;
        int lane = threadIdx.x & 63;
        int code = (b - (M_ROWS * DDIM) / 1024) * 4 + wave;
        const float4* ep = (const float4*)(emb + (size_t)code * DDIM);
        size_t base4 = (size_t)code * (DDIM / 4);
        float s = 0.f;
        #pragma unroll
        for (int j = 0; j < 2; ++j) {
            int c = lane + 64 * j;
            float4 e = ep[c];
            s += e.x * e.x + e.y * e.y + e.z * e.z + e.w * e.w;
            ushort4 h;
            h.x = bf16_rne(e.x); h.y = bf16_rne(e.y);
            h.z = bf16_rne(e.z); h.w = bf16_rne(e.w);
            eh[base4 + c] = h;
        }
        #pragma unroll
        for (int off = 32; off; off >>= 1) s += __shfl_down(s, off, 64);
        if (lane == 0) e_norms[code] = s;
    }
}

// ---------------------------------------------------------------------------
// Kernel 2: phase-1 coarse GEMM — 256x256 8-phase structure, 2-JOB blocks.
// Grid (32,32) = 1024 blocks; block = 2 consecutive 256-row tiles x 1
// 256-col panel. Grid-order locality is R4-identical (same col per block,
// adjacent rows; logical A/B traffic unchanged) — unlike R5/R7 persistence,
// which remapped block->work and collapsed locality (FETCH 272/511 MB).
// Cross-job pipeline (machinery verified R5/R7): last PH_ITER of job 0
// stages job 1's K-tiles 0,1 -> prologue stall + drain paid once per block
// instead of once per tile (halves the per-CU fill/drain count vs R4).
// MFMA per-accumulator K-order identical -> chunkmin bit-identical.
// vmcnt invariant: entering any PH_ITER, 8 outstanding = buf1's stage;
// ph4's vmcnt(8) retires buf1, ph8's retires next buf0.
// ---------------------------------------------------------------------------
__device__ __forceinline__ void stage_tile(const char* gbase, int kt,
                                           void* lds, int tid) {
    #pragma unroll
    for (int s = 0; s < 4; ++s) {
        const int row_l = (s << 6) + (tid >> 3);
        const int cb = (((tid & 7) ^ (row_l & 7)) << 4);
        const char* g = gbase + (size_t)row_l * (DDIM * 2) + ((size_t)kt << 7) + cb;
        char* l = (char*)lds + (s << 13) + (tid << 4);
        gl_lds16(g, l);
    }
}

#define BAR() __builtin_amdgcn_s_barrier()
#define LGK0() do { asm volatile("s_waitcnt lgkmcnt(0)" ::: "memory"); \
                    __builtin_amdgcn_sched_barrier(0); } while (0)
#define VMC8() do { asm volatile("s_waitcnt vmcnt(8)" ::: "memory"); } while (0)
#define VMC0() do { asm volatile("s_waitcnt vmcnt(0)" ::: "memory"); } while (0)
// conditional waits for the job-boundary PH_ITER ("last" from enclosing scope)
#define VMA_SEL() do { if (last) { VMC0(); } else { VMC8(); } } while (0)
#define VMB_SEL() do { if (!last) { VMC8(); } } while (0)

#define LDA(BUF, MH) do {                                                      \
    _Pragma("unroll") for (int i_ = 0; i_ < 4; ++i_) {                         \
        _Pragma("unroll") for (int kk_ = 0; kk_ < 2; ++kk_) {                  \
            const int row_ = (wm << 7) + ((((MH) << 2) + i_) << 4) + fr;       \
            const int cb_ = (kk_ << 6) + fkb;                                  \
            a[i_][kk_] = *(const short8*)((const char*)&ldsA[BUF][0][0]        \
                + row_ * 128 + (cb_ ^ ((row_ & 7) << 4)));                     \
        } } } while (0)

#define LDB(BUF, NH) do {                                                      \
    _Pragma("unroll") for (int j_ = 0; j_ < 2; ++j_) {                         \
        _Pragma("unroll") for (int kk_ = 0; kk_ < 2; ++kk_) {                  \
            const int row_ = (wn << 6) + ((((NH) << 1) + j_) << 4) + fr;       \
            const int cb_ = (kk_ << 6) + fkb;                                  \
            b[(NH) * 2 + j_][kk_] = *(const short8*)((const char*)&ldsB[BUF][0][0] \
                + row_ * 128 + (cb_ ^ ((row_ & 7) << 4)));                     \
        } } } while (0)

#define MFMA_Q(MH, NH) do {                                                    \
    __builtin_amdgcn_s_setprio(1);                                             \
    _Pragma("unroll") for (int i_ = 0; i_ < 4; ++i_) {                         \
        _Pragma("unroll") for (int j_ = 0; j_ < 2; ++j_) {                     \
            _Pragma("unroll") for (int kk_ = 0; kk_ < 2; ++kk_) {              \
                acc[(MH) * 4 + i_][(NH) * 2 + j_] =                            \
                    __builtin_amdgcn_mfma_f32_16x16x32_bf16(                   \
                        a[i_][kk_], b[(NH) * 2 + j_][kk_],                     \
                        acc[(MH) * 4 + i_][(NH) * 2 + j_], 0, 0, 0);           \
        } } }                                                                  \
    __builtin_amdgcn_s_setprio(0);                                             \
} while (0)

#define PH_ITER(SE, VMA, VMB, PA, PB, NK0, NK1)                                \
    LDA(0, 0); LDB(0, 0);                                                      \
    BAR(); LGK0(); MFMA_Q(0, 0); BAR();                                        \
    LDB(0, 1);                                                                 \
    BAR(); LGK0(); MFMA_Q(0, 1); BAR();                                        \
    LDA(0, 1);                                                                 \
    if (SE) stage_tile((PB), (NK0), &ldsB[0][0][0], tid);                      \
    BAR(); LGK0(); MFMA_Q(1, 0); BAR();                                        \
    if (SE) stage_tile((PA), (NK0), &ldsA[0][0][0], tid);                      \
    BAR(); MFMA_Q(1, 1); VMA; BAR();                                           \
    LDA(1, 0); LDB(1, 0);                                                      \
    BAR(); LGK0(); MFMA_Q(0, 0); BAR();                                        \
    LDB(1, 1);                                                                 \
    BAR(); LGK0(); MFMA_Q(0, 1); BAR();                                        \
    LDA(1, 1);                                                                 \
    if (SE) stage_tile((PB), (NK1), &ldsB[1][0][0], tid);                      \
    BAR(); LGK0(); MFMA_Q(1, 0); BAR();                                        \
    if (SE) stage_tile((PA), (NK1), &ldsA[1][0][0], tid);                      \
    BAR(); MFMA_Q(1, 1); VMB; BAR();

__global__ __launch_bounds__(512, 2) void vq_phase1(
    const u16* __restrict__ z_hi, const u16* __restrict__ e_hi,
    const float* __restrict__ e_norms,
    float* __restrict__ chunkmin) {
    __shared__ __align__(16) u16 ldsA[2][256][64];   // 64 KB
    __shared__ __align__(16) u16 ldsB[2][256][64];   // 64 KB

    const int tid  = threadIdx.x;
    const int lane = tid & 63;
    const int wid  = tid >> 6;
    const int wm   = wid >> 2;          // 0..1
    const int wn   = wid & 3;           // 0..3
    const int fr   = lane & 15;
    const int fkb  = (lane >> 4) << 4;  // k byte offset within 32-elem slice

    // 2-job mapping: block = row-tiles {2*bx, 2*bx+1} x col panel by.
    const int brow0 = blockIdx.x << 1;            // first row-tile index
    const int col0  = blockIdx.y << 8;

    const char* gAb = (const char*)z_hi;
    const char* gB0 = (const char*)e_hi + (size_t)col0 * (DDIM * 2);

    f32x4 acc[8][4];
    short8 a[4][2], b[4][2];

    // epilogue constants (col panel fixed across jobs — hoisted)
    const int cn = lane & 15;
    const int cg = lane >> 4;
    float en[4];
    #pragma unroll
    for (int j = 0; j < 4; ++j) en[j] = e_norms[col0 + (wn << 6) + j * 16 + cn];

    // prologue: job 0, K-tiles 0 (buf0) and 1 (buf1)
    {
        const char* gA = gAb + ((size_t)brow0 << 8) * (DDIM * 2);
        stage_tile(gA, 0, &ldsA[0][0][0], tid);
        stage_tile(gB0, 0, &ldsB[0][0][0], tid);
        stage_tile(gA, 1, &ldsA[1][0][0], tid);
        stage_tile(gB0, 1, &ldsB[1][0][0], tid);
    }
    VMC8(); BAR();

    #pragma unroll 1
    for (int job = 0; job < 2; ++job) {
        const int row0 = (brow0 + job) << 8;
        const char* gAj = gAb + (size_t)row0 * (DDIM * 2);
        const bool last = (job == 1);
        // next job's A tile (unused when last; kept in-bounds)
        const char* gAn = last ? gAj : (gAj + (size_t)256 * (DDIM * 2));

        const f32x4 zf = {0.f, 0.f, 0.f, 0.f};
        #pragma unroll
        for (int i = 0; i < 8; ++i)
            #pragma unroll
            for (int j = 0; j < 4; ++j) acc[i][j] = zf;

        // pairs 0..2: consume K-tiles (2t,2t+1), stage (2t+2,2t+3) same job
        PH_ITER(1, VMC8(), VMC8(), gAj, gB0, 2, 3)
        PH_ITER(1, VMC8(), VMC8(), gAj, gB0, 4, 5)
        PH_ITER(1, VMC8(), VMC8(), gAj, gB0, 6, 7)
        // boundary pair: consume tiles (6,7); stage NEXT job's tiles (0,1).
        // On the last job: no stages, drain with vmcnt(0) before buf1 use.
        PH_ITER(!last, VMA_SEL(), VMB_SEL(), gAn, gB0, 0, 1)

        // epilogue: C layout col = lane&15, row = (lane>>4)*4 + reg.
        #pragma unroll
        for (int i = 0; i < 8; ++i)
            #pragma unroll
            for (int r = 0; r < 4; ++r) {
                float mv[4];
                #pragma unroll
                for (int j = 0; j < 4; ++j) mv[j] = en[j] - 2.0f * acc[i][j][r];

                #pragma unroll
                for (int k = 0; k < 2; ++k) {
                    float lo = mv[k], hi = mv[k + 2];
                    float mine = (lane & 8) ? hi : lo;
                    float thrs = (lane & 8) ? lo : hi;
                    mv[k] = fminf(mine, __shfl_xor(thrs, 8, 64));
                }
                {
                    float lo = mv[0], hi = mv[1];
                    float mine = (lane & 4) ? hi : lo;
                    float thrs = (lane & 4) ? lo : hi;
                    mv[0] = fminf(mine, __shfl_xor(thrs, 4, 64));
                }
                mv[0] = fminf(mv[0], dpp_mov<0xB1>(mv[0]));
                mv[0] = fminf(mv[0], dpp_mov<0x4E>(mv[0]));

                if ((cn & 3) == 0) {
                    const int jj = ((cn >> 3) << 1) | ((cn >> 2) & 1);
                    const int row_g = row0 + (wm << 7) + (i << 4) + (cg << 2) + r;
                    chunkmin[(size_t)row_g * NCHUNK + (col0 >> 4) + (wn << 2) + jj] = mv[0];
                }
            }
    }
}

// ---------------------------------------------------------------------------
// Kernel 3a: threshold + candidate masks (R6-exact). One wave per row.
// Reads the chunkmin row, computes thr = min + MARGIN, ballots the 8 mask
// words, lane0 writes them IN-PLACE into the row prefix (64 B). Minima are
// fully consumed (registers) before the overwrite. Measured ~8 us.
// ---------------------------------------------------------------------------
__global__ __launch_bounds__(256) void vq_fin_a(
    float* __restrict__ chunkmin) {
    const int wave = threadIdx.x >> 6;
    const int lane = threadIdx.x & 63;
    const int row  = blockIdx.x * 4 + wave;

    float* cmrow = chunkmin + (size_t)row * NCHUNK;
    const float4* cm4 = (const float4*)cmrow;
    float4 v0 = cm4[lane];
    float4 v1 = cm4[64 + lane];
    float m = fminf(fminf(fminf(v0.x, v0.y), fminf(v0.z, v0.w)),
                    fminf(fminf(v1.x, v1.y), fminf(v1.z, v1.w)));
    #pragma unroll
    for (int off = 1; off < 64; off <<= 1) m = fminf(m, __shfl_xor(m, off, 64));
    const float thr = m + MARGIN;

    u64 msk[8];
    msk[0] = __ballot(v0.x <= thr);
    msk[1] = __ballot(v0.y <= thr);
    msk[2] = __ballot(v0.z <= thr);
    msk[3] = __ballot(v0.w <= thr);
    msk[4] = __ballot(v1.x <= thr);
    msk[5] = __ballot(v1.y <= thr);
    msk[6] = __ballot(v1.z <= thr);
    msk[7] = __ballot(v1.w <= thr);

    if (lane == 0) {
        u64* mrow = (u64*)cmrow;
        #pragma unroll
        for (int i = 0; i < 8; ++i) mrow[i] = msk[i];
    }
}

// ---------------------------------------------------------------------------
// Kernel 3b: exact re-eval + winner gather (R6-exact structure).
// Reads the 8 mask words (64 B/row), evaluates candidate 16-code chunks in
// exact fp32 (reduce-scatter butterfly; lane owns code bitrev4(lane&15)),
// wave argmin, gather, outputs, loss partial. NO fences (R7 lesson: a
// per-block __threadfence for fused loss flushes L2 and tripled this
// kernel). chunkmin row overwritten by out_q at the end (alias-safe).
// ---------------------------------------------------------------------------
__global__ __launch_bounds__(256) void vq_fin_b(
    const float* __restrict__ z, const float* __restrict__ emb,
    const float* __restrict__ e_norms, const float* __restrict__ chunkmin,
    float* __restrict__ out_q, float* __restrict__ out_idx,
    float* __restrict__ partials) {
    const int wave = threadIdx.x >> 6;
    const int lane = threadIdx.x & 63;
    const int row  = blockIdx.x * 4 + wave;

    const u64* mrow = (const u64*)(chunkmin + (size_t)row * NCHUNK);
    u64 msk[8];
    #pragma unroll
    for (int i = 0; i < 8; ++i) msk[i] = mrow[i];

    const float4* z4 = (const float4*)(z + (size_t)row * DDIM);
    float4 za = z4[2 * lane];
    float4 zb = z4[2 * lane + 1];

    const int cown = ((lane & 1) << 3) | ((lane & 2) << 1)
                   | ((lane & 4) >> 1) | ((lane & 8) >> 3);

    u64 best = 0xFFFFFFFFFFFFFFFFull;
    #pragma unroll
    for (int p = 0; p < 2; ++p)
        #pragma unroll
        for (int j = 0; j < 4; ++j) {
            u64 mk = msk[p * 4 + j];
            while (mk) {
                int l = __ffsll((long long)mk) - 1;
                mk &= mk - 1;
                const int chunk = (p << 8) + (l << 2) + j;
                const int cbase = chunk << 4;
                const float* eb = emb + (size_t)cbase * DDIM + lane * 8;
                float part[16];
                #pragma unroll
                for (int k = 0; k < 16; ++k) {
                    float4 ea = *(const float4*)(eb + (size_t)k * DDIM);
                    float4 e2 = *(const float4*)(eb + (size_t)k * DDIM + 4);
                    part[k] = za.x * ea.x + za.y * ea.y + za.z * ea.z + za.w * ea.w
                            + zb.x * e2.x + zb.y * e2.y + zb.z * e2.z + zb.w * e2.w;
                }
                #pragma unroll
                for (int k = 0; k < 8; ++k) {            // xor1 (DPP)
                    float lo = part[k], hi = part[k + 8];
                    float mine = (lane & 1) ? hi : lo;
                    float thrs = (lane & 1) ? lo : hi;
                    part[k] = mine + dpp_mov<0xB1>(thrs);
                }
                #pragma unroll
                for (int k = 0; k < 4; ++k) {            // xor2 (DPP)
                    float lo = part[k], hi = part[k + 4];
                    float mine = (lane & 2) ? hi : lo;
                    float thrs = (lane & 2) ? lo : hi;
                    part[k] = mine + dpp_mov<0x4E>(thrs);
                }
                #pragma unroll
                for (int k = 0; k < 2; ++k) {            // xor4
                    float lo = part[k], hi = part[k + 2];
                    float mine = (lane & 4) ? hi : lo;
                    float thrs = (lane & 4) ? lo : hi;
                    part[k] = mine + __shfl_xor(thrs, 4, 64);
                }
                {                                         // xor8
                    float lo = part[0], hi = part[1];
                    float mine = (lane & 8) ? hi : lo;
                    float thrs = (lane & 8) ? lo : hi;
                    part[0] = mine + __shfl_xor(thrs, 8, 64);
                }
                part[0] += __shfl_xor(part[0], 16, 64);
                part[0] += __shfl_xor(part[0], 32, 64);

                const int ci = cbase + cown;
                float dist = e_norms[ci] - 2.0f * part[0];
                best = umin64(best, ((u64)float_to_ordered(dist) << 32) | (u32)ci);
            }
        }

    #pragma unroll
    for (int off = 1; off < 64; off <<= 1)
        best = umin64(best, __shfl_xor(best, off, 64));

    const int idx = (int)(best & 0xFFFFFFFFull);
    const float* ew = emb + (size_t)idx * DDIM + lane * 8;
    float4 qa = *(const float4*)ew;
    float4 qb = *(const float4*)(ew + 4);
    float4* op = (float4*)(out_q + (size_t)row * DDIM);
    op[2 * lane]     = qa;
    op[2 * lane + 1] = qb;

    float dx, local = 0.f;
    dx = za.x - qa.x; local += dx * dx;  dx = za.y - qa.y; local += dx * dx;
    dx = za.z - qa.z; local += dx * dx;  dx = za.w - qa.w; local += dx * dx;
    dx = zb.x - qb.x; local += dx * dx;  dx = zb.y - qb.y; local += dx * dx;
    dx = zb.z - qb.z; local += dx * dx;  dx = zb.w - qb.w; local += dx * dx;
    #pragma unroll
    for (int off = 32; off; off >>= 1) local += __shfl_down(local, off, 64);

    __shared__ float wsum[4];
    if (lane == 0) { wsum[wave] = local; out_idx[row] = (float)idx; }
    __syncthreads();
    if (threadIdx.x == 0)
        partials[blockIdx.x] = wsum[0] + wsum[1] + wsum[2] + wsum[3];
}

// ---------------------------------------------------------------------------
// Kernel 4: reduce 4096 loss partials -> scalar loss. Kept as its own tiny
// dispatch: fusing it into fin_b requires a device-scope fence per block,
// which flushes L2 and regressed fin_b 3x (R7).
// ---------------------------------------------------------------------------
__global__ __launch_bounds__(256) void vq_loss_reduce(
    const float* __restrict__ partials, float* __restrict__ out_loss) {
    __shared__ float red[256];
    float s = 0.f;
    for (int i = threadIdx.x; i < M_ROWS / 4; i += 256) s += partials[i];
    red[threadIdx.x] = s;
    __syncthreads();
    for (int off = 128; off; off >>= 1) {
        if (threadIdx.x < off) red[threadIdx.x] += red[threadIdx.x + off];
        __syncthreads();
    }
    if (threadIdx.x == 0)
        out_loss[0] = 0.25f * red[0] / ((float)M_ROWS * (float)DDIM);
}

extern "C" void kernel_launch(void* const* d_in, const int* in_sizes, int n_in,
                              void* d_out, int out_size, void* d_ws, size_t ws_size,
                              hipStream_t stream) {
    (void)in_sizes; (void)n_in; (void)out_size; (void)ws_size;
    const float* z   = (const float*)d_in[0];   // [16384, 512]
    const float* emb = (const float*)d_in[1];   // [8192, 512]

    float* out      = (float*)d_out;
    float* out_q    = out;
    float* out_idx  = out + (size_t)M_ROWS * DDIM;
    float* out_loss = out + (size_t)M_ROWS * DDIM + M_ROWS;

    // ws layout (requires ws_size >= 49152 + 24 MB):
    //   [0,32K) e_norms | [32K,48K) partials | [48K,+16MB) z_hi | +8MB e_hi
    char* ws = (char*)d_ws;
    float* e_norms  = (float*)ws;
    float* partials = (float*)(ws + 32768);
    u16* z_hi = (u16*)(ws + 49152);
    u16* e_hi = (u16*)(ws + 49152 + (size_t)M_ROWS * DDIM * 2);

    // chunkmin [16384][512] f32 = 32 MB aliases out_q EXACTLY (2048 B/row).
    // phase1 fills it; fin_a consumes each row then overwrites its prefix
    // with the candidate masks; fin_b reads the masks, then overwrites the
    // row with out_q. Stream-ordered, wave-private rows -> race-free.
    float* chunkmin = out_q;

    const int zblocks = (M_ROWS * DDIM) / 1024;      // 16384
    const int eblocks = N_CODES / 4;                 // 2048
    vq_prep<<<zblocks + eblocks, 256, 0, stream>>>(
        (const float4*)z, (ushort4*)z_hi, emb, (ushort4*)e_hi, e_norms);

    // 2-job blocks: grid (rows/512, cols/256) = (32, 32).
    vq_phase1<<<dim3(M_ROWS / 512, N_CODES / 256), 512, 0, stream>>>(
        z_hi, e_hi, e_norms, chunkmin);

    vq_fin_a<<<M_ROWS / 4, 256, 0, stream>>>(chunkmin);

    vq_fin_b<<<M_ROWS / 4, 256, 0, stream>>>(
        z, emb, e_norms, chunkmin, out_q, out_idx, partials);

    vq_loss_reduce<<<1, 256, 0, stream>>>(partials, out_loss);
}

// Round 10
// 333.457 us; speedup vs baseline: 1.3458x; 1.3458x over previous
//
#include <hip/hip_runtime.h>
#include <hip/hip_bf16.h>

#define M_ROWS 16384
#define N_CODES 8192
#define DDIM    512
#define NCHUNK  512          // 16-code chunks per row
#define MARGIN  1.5f         // coarse-vs-exact margin. Coarse bf16-GEMM error
                             // std ~0.125 abs (2*sqrt(1024)*2^-9); threshold
                             // needs eps1+eps2 (std ~0.18); 1.5 = 8 sigma ->
                             // P(miss) ~1e-17/row. Validated R9 (passed,
                             // absmax unchanged, fin_b -23 us).

typedef unsigned int u32;
typedef unsigned long long u64;
typedef unsigned short u16;
typedef __attribute__((ext_vector_type(8))) short short8;   // 8 bf16 = 4 VGPRs
typedef __attribute__((ext_vector_type(4))) float f32x4;

__device__ __forceinline__ u32 float_to_ordered(float f) {
    u32 u = __float_as_uint(f);
    return (u & 0x80000000u) ? ~u : (u | 0x80000000u);
}

__device__ __forceinline__ u16 bf16_rne(float x) {
    u32 u = __float_as_uint(x);
    u32 r = u + 0x7FFFu + ((u >> 16) & 1u);
    return (u16)(r >> 16);
}

__device__ __forceinline__ void gl_lds16(const void* g, void* l) {
    __builtin_amdgcn_global_load_lds((const __attribute__((address_space(1))) u32*)g,
                                     (__attribute__((address_space(3))) u32*)l,
                                     16, 0, 0);
}

__device__ __forceinline__ u64 umin64(u64 a, u64 b) { return a < b ? a : b; }

// DPP lane-permute within quads (VALU pipe, avoids ds_bpermute).
// 0xB1 = quad_perm [1,0,3,2] = xor 1;  0x4E = quad_perm [2,3,0,1] = xor 2.
#if __has_builtin(__builtin_amdgcn_update_dpp)
template <int CTRL>
__device__ __forceinline__ float dpp_mov(float x) {
    return __int_as_float(__builtin_amdgcn_update_dpp(
        __float_as_int(x), __float_as_int(x), CTRL, 0xF, 0xF, true));
}
#else
template <int CTRL>
__device__ __forceinline__ float dpp_mov(float x) {
    return __shfl_xor(x, CTRL == 0xB1 ? 1 : 2, 64);
}
#endif

// ---------------------------------------------------------------------------
// Kernel 1: prep (R4-exact).
// ---------------------------------------------------------------------------
__global__ __launch_bounds__(256) void vq_prep(
    const float4* __restrict__ z4, ushort4* __restrict__ zh,
    const float* __restrict__ emb, ushort4* __restrict__ eh,
    float* __restrict__ e_norms) {
    int b = blockIdx.x;
    if (b < (M_ROWS * DDIM) / 1024) {
        int i = b * 256 + threadIdx.x;
        float4 v = z4[i];
        ushort4 h;
        h.x = bf16_rne(v.x); h.y = bf16_rne(v.y);
        h.z = bf16_rne(v.z); h.w = bf16_rne(v.w);
        zh[i] = h;
    } else {
        int wave = threadIdx.x >> 6;
        int lane = threadIdx.x & 63;
        int code = (b - (M_ROWS * DDIM) / 1024) * 4 + wave;
        const float4* ep = (const float4*)(emb + (size_t)code * DDIM);
        size_t base4 = (size_t)code * (DDIM / 4);
        float s = 0.f;
        #pragma unroll
        for (int j = 0; j < 2; ++j) {
            int c = lane + 64 * j;
            float4 e = ep[c];
            s += e.x * e.x + e.y * e.y + e.z * e.z + e.w * e.w;
            ushort4 h;
            h.x = bf16_rne(e.x); h.y = bf16_rne(e.y);
            h.z = bf16_rne(e.z); h.w = bf16_rne(e.w);
            eh[base4 + c] = h;
        }
        #pragma unroll
        for (int off = 32; off; off >>= 1) s += __shfl_down(s, off, 64);
        if (lane == 0) e_norms[code] = s;
    }
}

// ---------------------------------------------------------------------------
// Kernel 2: phase-1 coarse GEMM — R4/R8-EXACT 256x256 8-phase structure,
// grid (64,32) x-major, ONE tile per block. This grid is L2-CAPACITY-
// CRITICAL: each XCD's 32 co-resident blocks = 8 row-tiles x 4 col-panels
// = 2 MB A + 2 MB B = exactly the 4 MB XCD L2. Every remapping attempt
// (R5 persistent: 272 MB FETCH; R7 XCD-persistent: 511 MB; R9 2-job
// blocks: 259 MB FETCH + 7x write amplification from evicted half-lines)
// broke this budget and regressed. DO NOT change block->work mapping.
// Measured: 171.5 us, FETCH 58 MB, WRITE 32 MB, MfmaUtil 33.5, conflicts 0.
// ---------------------------------------------------------------------------
__device__ __forceinline__ void stage_tile(const char* gbase, int kt,
                                           void* lds, int tid) {
    #pragma unroll
    for (int s = 0; s < 4; ++s) {
        const int row_l = (s << 6) + (tid >> 3);
        const int cb = (((tid & 7) ^ (row_l & 7)) << 4);
        const char* g = gbase + (size_t)row_l * (DDIM * 2) + ((size_t)kt << 7) + cb;
        char* l = (char*)lds + (s << 13) + (tid << 4);
        gl_lds16(g, l);
    }
}

#define BAR() __builtin_amdgcn_s_barrier()
#define LGK0() do { asm volatile("s_waitcnt lgkmcnt(0)" ::: "memory"); \
                    __builtin_amdgcn_sched_barrier(0); } while (0)
#define VMC8() do { asm volatile("s_waitcnt vmcnt(8)" ::: "memory"); } while (0)
#define VMC0() do { asm volatile("s_waitcnt vmcnt(0)" ::: "memory"); } while (0)

#define LDA(BUF, MH) do {                                                      \
    _Pragma("unroll") for (int i_ = 0; i_ < 4; ++i_) {                         \
        _Pragma("unroll") for (int kk_ = 0; kk_ < 2; ++kk_) {                  \
            const int row_ = (wm << 7) + ((((MH) << 2) + i_) << 4) + fr;       \
            const int cb_ = (kk_ << 6) + fkb;                                  \
            a[i_][kk_] = *(const short8*)((const char*)&ldsA[BUF][0][0]        \
                + row_ * 128 + (cb_ ^ ((row_ & 7) << 4)));                     \
        } } } while (0)

#define LDB(BUF, NH) do {                                                      \
    _Pragma("unroll") for (int j_ = 0; j_ < 2; ++j_) {                         \
        _Pragma("unroll") for (int kk_ = 0; kk_ < 2; ++kk_) {                  \
            const int row_ = (wn << 6) + ((((NH) << 1) + j_) << 4) + fr;       \
            const int cb_ = (kk_ << 6) + fkb;                                  \
            b[(NH) * 2 + j_][kk_] = *(const short8*)((const char*)&ldsB[BUF][0][0] \
                + row_ * 128 + (cb_ ^ ((row_ & 7) << 4)));                     \
        } } } while (0)

#define MFMA_Q(MH, NH) do {                                                    \
    __builtin_amdgcn_s_setprio(1);                                             \
    _Pragma("unroll") for (int i_ = 0; i_ < 4; ++i_) {                         \
        _Pragma("unroll") for (int j_ = 0; j_ < 2; ++j_) {                     \
            _Pragma("unroll") for (int kk_ = 0; kk_ < 2; ++kk_) {              \
                acc[(MH) * 4 + i_][(NH) * 2 + j_] =                            \
                    __builtin_amdgcn_mfma_f32_16x16x32_bf16(                   \
                        a[i_][kk_], b[(NH) * 2 + j_][kk_],                     \
                        acc[(MH) * 4 + i_][(NH) * 2 + j_], 0, 0, 0);           \
        } } }                                                                  \
    __builtin_amdgcn_s_setprio(0);                                             \
} while (0)

#define PH_ITER(SE, VMA, VMB, NK0, NK1)                                        \
    LDA(0, 0); LDB(0, 0);                                                      \
    BAR(); LGK0(); MFMA_Q(0, 0); BAR();                                        \
    LDB(0, 1);                                                                 \
    BAR(); LGK0(); MFMA_Q(0, 1); BAR();                                        \
    LDA(0, 1);                                                                 \
    if (SE) stage_tile(gB0, (NK0), &ldsB[0][0][0], tid);                       \
    BAR(); LGK0(); MFMA_Q(1, 0); BAR();                                        \
    if (SE) stage_tile(gA0, (NK0), &ldsA[0][0][0], tid);                       \
    BAR(); MFMA_Q(1, 1); VMA; BAR();                                           \
    LDA(1, 0); LDB(1, 0);                                                      \
    BAR(); LGK0(); MFMA_Q(0, 0); BAR();                                        \
    LDB(1, 1);                                                                 \
    BAR(); LGK0(); MFMA_Q(0, 1); BAR();                                        \
    LDA(1, 1);                                                                 \
    if (SE) stage_tile(gB0, (NK1), &ldsB[1][0][0], tid);                       \
    BAR(); LGK0(); MFMA_Q(1, 0); BAR();                                        \
    if (SE) stage_tile(gA0, (NK1), &ldsA[1][0][0], tid);                       \
    BAR(); MFMA_Q(1, 1); VMB; BAR();

__global__ __launch_bounds__(512, 2) void vq_phase1(
    const u16* __restrict__ z_hi, const u16* __restrict__ e_hi,
    const float* __restrict__ e_norms,
    float* __restrict__ chunkmin) {
    __shared__ __align__(16) u16 ldsA[2][256][64];   // 64 KB
    __shared__ __align__(16) u16 ldsB[2][256][64];   // 64 KB

    const int tid  = threadIdx.x;
    const int lane = tid & 63;
    const int wid  = tid >> 6;
    const int wm   = wid >> 2;          // 0..1
    const int wn   = wid & 3;           // 0..3
    const int row0 = blockIdx.x << 8;
    const int col0 = blockIdx.y << 8;
    const int fr   = lane & 15;
    const int fkb  = (lane >> 4) << 4;  // k byte offset within 32-elem slice

    const char* gA0 = (const char*)z_hi + (size_t)row0 * (DDIM * 2);
    const char* gB0 = (const char*)e_hi + (size_t)col0 * (DDIM * 2);

    f32x4 acc[8][4] = {};
    short8 a[4][2], b[4][2];

    // prologue: stage K-tiles 0 (buf0) and 1 (buf1)
    stage_tile(gA0, 0, &ldsA[0][0][0], tid);
    stage_tile(gB0, 0, &ldsB[0][0][0], tid);
    stage_tile(gA0, 1, &ldsA[1][0][0], tid);
    stage_tile(gB0, 1, &ldsB[1][0][0], tid);
    VMC8(); BAR();

    #pragma unroll 1
    for (int t = 0; t < 3; ++t) {
        const int nk0 = 2 * t + 2, nk1 = 2 * t + 3;
        PH_ITER(1, VMC8(), VMC8(), nk0, nk1)
    }
    // drain iteration: no stages; vmcnt(0) before buf1 phases.
    PH_ITER(0, VMC0(), ((void)0), 0, 0)

    // epilogue: C layout col = lane&15, row = (lane>>4)*4 + reg.
    const int cn = lane & 15;
    const int cg = lane >> 4;
    float en[4];
    #pragma unroll
    for (int j = 0; j < 4; ++j) en[j] = e_norms[col0 + (wn << 6) + j * 16 + cn];

    #pragma unroll
    for (int i = 0; i < 8; ++i)
        #pragma unroll
        for (int r = 0; r < 4; ++r) {
            float mv[4];
            #pragma unroll
            for (int j = 0; j < 4; ++j) mv[j] = en[j] - 2.0f * acc[i][j][r];

            #pragma unroll
            for (int k = 0; k < 2; ++k) {
                float lo = mv[k], hi = mv[k + 2];
                float mine = (lane & 8) ? hi : lo;
                float thrs = (lane & 8) ? lo : hi;
                mv[k] = fminf(mine, __shfl_xor(thrs, 8, 64));
            }
            {
                float lo = mv[0], hi = mv[1];
                float mine = (lane & 4) ? hi : lo;
                float thrs = (lane & 4) ? lo : hi;
                mv[0] = fminf(mine, __shfl_xor(thrs, 4, 64));
            }
            mv[0] = fminf(mv[0], dpp_mov<0xB1>(mv[0]));
            mv[0] = fminf(mv[0], dpp_mov<0x4E>(mv[0]));

            if ((cn & 3) == 0) {
                const int jj = ((cn >> 3) << 1) | ((cn >> 2) & 1);
                const int row_g = row0 + (wm << 7) + (i << 4) + (cg << 2) + r;
                chunkmin[(size_t)row_g * NCHUNK + (col0 >> 4) + (wn << 2) + jj] = mv[0];
            }
        }
}

// ---------------------------------------------------------------------------
// Kernel 3a: threshold + candidate masks (R6-exact). One wave per row.
// Reads the chunkmin row, computes thr = min + MARGIN, ballots the 8 mask
// words, lane0 writes them IN-PLACE into the row prefix (64 B). Minima are
// fully consumed (registers) before the overwrite. Measured ~8 us.
// ---------------------------------------------------------------------------
__global__ __launch_bounds__(256) void vq_fin_a(
    float* __restrict__ chunkmin) {
    const int wave = threadIdx.x >> 6;
    const int lane = threadIdx.x & 63;
    const int row  = blockIdx.x * 4 + wave;

    float* cmrow = chunkmin + (size_t)row * NCHUNK;
    const float4* cm4 = (const float4*)cmrow;
    float4 v0 = cm4[lane];
    float4 v1 = cm4[64 + lane];
    float m = fminf(fminf(fminf(v0.x, v0.y), fminf(v0.z, v0.w)),
                    fminf(fminf(v1.x, v1.y), fminf(v1.z, v1.w)));
    #pragma unroll
    for (int off = 1; off < 64; off <<= 1) m = fminf(m, __shfl_xor(m, off, 64));
    const float thr = m + MARGIN;

    u64 msk[8];
    msk[0] = __ballot(v0.x <= thr);
    msk[1] = __ballot(v0.y <= thr);
    msk[2] = __ballot(v0.z <= thr);
    msk[3] = __ballot(v0.w <= thr);
    msk[4] = __ballot(v1.x <= thr);
    msk[5] = __ballot(v1.y <= thr);
    msk[6] = __ballot(v1.z <= thr);
    msk[7] = __ballot(v1.w <= thr);

    if (lane == 0) {
        u64* mrow = (u64*)cmrow;
        #pragma unroll
        for (int i = 0; i < 8; ++i) mrow[i] = msk[i];
    }
}

// ---------------------------------------------------------------------------
// Kernel 3b: exact re-eval + winner gather (R6-exact structure).
// Reads the 8 mask words (64 B/row), evaluates candidate 16-code chunks in
// exact fp32 (reduce-scatter butterfly; lane owns code bitrev4(lane&15)),
// wave argmin, gather, outputs, loss partial. NO fences (R7 lesson: a
// per-block __threadfence for fused loss flushes L2 and tripled this
// kernel). chunkmin row overwritten by out_q at the end (alias-safe).
// ---------------------------------------------------------------------------
__global__ __launch_bounds__(256) void vq_fin_b(
    const float* __restrict__ z, const float* __restrict__ emb,
    const float* __restrict__ e_norms, const float* __restrict__ chunkmin,
    float* __restrict__ out_q, float* __restrict__ out_idx,
    float* __restrict__ partials) {
    const int wave = threadIdx.x >> 6;
    const int lane = threadIdx.x & 63;
    const int row  = blockIdx.x * 4 + wave;

    const u64* mrow = (const u64*)(chunkmin + (size_t)row * NCHUNK);
    u64 msk[8];
    #pragma unroll
    for (int i = 0; i < 8; ++i) msk[i] = mrow[i];

    const float4* z4 = (const float4*)(z + (size_t)row * DDIM);
    float4 za = z4[2 * lane];
    float4 zb = z4[2 * lane + 1];

    const int cown = ((lane & 1) << 3) | ((lane & 2) << 1)
                   | ((lane & 4) >> 1) | ((lane & 8) >> 3);

    u64 best = 0xFFFFFFFFFFFFFFFFull;
    #pragma unroll
    for (int p = 0; p < 2; ++p)
        #pragma unroll
        for (int j = 0; j < 4; ++j) {
            u64 mk = msk[p * 4 + j];
            while (mk) {
                int l = __ffsll((long long)mk) - 1;
                mk &= mk - 1;
                const int chunk = (p << 8) + (l << 2) + j;
                const int cbase = chunk << 4;
                const float* eb = emb + (size_t)cbase * DDIM + lane * 8;
                float part[16];
                #pragma unroll
                for (int k = 0; k < 16; ++k) {
                    float4 ea = *(const float4*)(eb + (size_t)k * DDIM);
                    float4 e2 = *(const float4*)(eb + (size_t)k * DDIM + 4);
                    part[k] = za.x * ea.x + za.y * ea.y + za.z * ea.z + za.w * ea.w
                            + zb.x * e2.x + zb.y * e2.y + zb.z * e2.z + zb.w * e2.w;
                }
                #pragma unroll
                for (int k = 0; k < 8; ++k) {            // xor1 (DPP)
                    float lo = part[k], hi = part[k + 8];
                    float mine = (lane & 1) ? hi : lo;
                    float thrs = (lane & 1) ? lo : hi;
                    part[k] = mine + dpp_mov<0xB1>(thrs);
                }
                #pragma unroll
                for (int k = 0; k < 4; ++k) {            // xor2 (DPP)
                    float lo = part[k], hi = part[k + 4];
                    float mine = (lane & 2) ? hi : lo;
                    float thrs = (lane & 2) ? lo : hi;
                    part[k] = mine + dpp_mov<0x4E>(thrs);
                }
                #pragma unroll
                for (int k = 0; k < 2; ++k) {            // xor4
                    float lo = part[k], hi = part[k + 2];
                    float mine = (lane & 4) ? hi : lo;
                    float thrs = (lane & 4) ? lo : hi;
                    part[k] = mine + __shfl_xor(thrs, 4, 64);
                }
                {                                         // xor8
                    float lo = part[0], hi = part[1];
                    float mine = (lane & 8) ? hi : lo;
                    float thrs = (lane & 8) ? lo : hi;
                    part[0] = mine + __shfl_xor(thrs, 8, 64);
                }
                part[0] += __shfl_xor(part[0], 16, 64);
                part[0] += __shfl_xor(part[0], 32, 64);

                const int ci = cbase + cown;
                float dist = e_norms[ci] - 2.0f * part[0];
                best = umin64(best, ((u64)float_to_ordered(dist) << 32) | (u32)ci);
            }
        }

    #pragma unroll
    for (int off = 1; off < 64; off <<= 1)
        best = umin64(best, __shfl_xor(best, off, 64));

    const int idx = (int)(best & 0xFFFFFFFFull);
    const float* ew = emb + (size_t)idx * DDIM + lane * 8;
    float4 qa = *(const float4*)ew;
    float4 qb = *(const float4*)(ew + 4);
    float4* op = (float4*)(out_q + (size_t)row * DDIM);
    op[2 * lane]     = qa;
    op[2 * lane + 1] = qb;

    float dx, local = 0.f;
    dx = za.x - qa.x; local += dx * dx;  dx = za.y - qa.y; local += dx * dx;
    dx = za.z - qa.z; local += dx * dx;  dx = za.w - qa.w; local += dx * dx;
    dx = zb.x - qb.x; local += dx * dx;  dx = zb.y - qb.y; local += dx * dx;
    dx = zb.z - qb.z; local += dx * dx;  dx = zb.w - qb.w; local += dx * dx;
    #pragma unroll
    for (int off = 32; off; off >>= 1) local += __shfl_down(local, off, 64);

    __shared__ float wsum[4];
    if (lane == 0) { wsum[wave] = local; out_idx[row] = (float)idx; }
    __syncthreads();
    if (threadIdx.x == 0)
        partials[blockIdx.x] = wsum[0] + wsum[1] + wsum[2] + wsum[3];
}

// ---------------------------------------------------------------------------
// Kernel 4: reduce 4096 loss partials -> scalar loss. Kept as its own tiny
// dispatch: fusing it into fin_b requires a device-scope fence per block,
// which flushes L2 and regressed fin_b 3x (R7).
// ---------------------------------------------------------------------------
__global__ __launch_bounds__(256) void vq_loss_reduce(
    const float* __restrict__ partials, float* __restrict__ out_loss) {
    __shared__ float red[256];
    float s = 0.f;
    for (int i = threadIdx.x; i < M_ROWS / 4; i += 256) s += partials[i];
    red[threadIdx.x] = s;
    __syncthreads();
    for (int off = 128; off; off >>= 1) {
        if (threadIdx.x < off) red[threadIdx.x] += red[threadIdx.x + off];
        __syncthreads();
    }
    if (threadIdx.x == 0)
        out_loss[0] = 0.25f * red[0] / ((float)M_ROWS * (float)DDIM);
}

extern "C" void kernel_launch(void* const* d_in, const int* in_sizes, int n_in,
                              void* d_out, int out_size, void* d_ws, size_t ws_size,
                              hipStream_t stream) {
    (void)in_sizes; (void)n_in; (void)out_size; (void)ws_size;
    const float* z   = (const float*)d_in[0];   // [16384, 512]
    const float* emb = (const float*)d_in[1];   // [8192, 512]

    float* out      = (float*)d_out;
    float* out_q    = out;
    float* out_idx  = out + (size_t)M_ROWS * DDIM;
    float* out_loss = out + (size_t)M_ROWS * DDIM + M_ROWS;

    // ws layout (requires ws_size >= 49152 + 24 MB):
    //   [0,32K) e_norms | [32K,48K) partials | [48K,+16MB) z_hi | +8MB e_hi
    char* ws = (char*)d_ws;
    float* e_norms  = (float*)ws;
    float* partials = (float*)(ws + 32768);
    u16* z_hi = (u16*)(ws + 49152);
    u16* e_hi = (u16*)(ws + 49152 + (size_t)M_ROWS * DDIM * 2);

    // chunkmin [16384][512] f32 = 32 MB aliases out_q EXACTLY (2048 B/row).
    // phase1 fills it; fin_a consumes each row then overwrites its prefix
    // with the candidate masks; fin_b reads the masks, then overwrites the
    // row with out_q. Stream-ordered, wave-private rows -> race-free.
    float* chunkmin = out_q;

    const int zblocks = (M_ROWS * DDIM) / 1024;      // 16384
    const int eblocks = N_CODES / 4;                 // 2048
    vq_prep<<<zblocks + eblocks, 256, 0, stream>>>(
        (const float4*)z, (ushort4*)z_hi, emb, (ushort4*)e_hi, e_norms);

    vq_phase1<<<dim3(M_ROWS / 256, N_CODES / 256), 512, 0, stream>>>(
        z_hi, e_hi, e_norms, chunkmin);

    vq_fin_a<<<M_ROWS / 4, 256, 0, stream>>>(chunkmin);

    vq_fin_b<<<M_ROWS / 4, 256, 0, stream>>>(
        z, emb, e_norms, chunkmin, out_q, out_idx, partials);

    vq_loss_reduce<<<1, 256, 0, stream>>>(partials, out_loss);
}

// Round 11
// 302.923 us; speedup vs baseline: 1.4815x; 1.1008x over previous
//
#include <hip/hip_runtime.h>
#include <hip/hip_bf16.h>
#include <hip/hip_fp16.h>

#define M_ROWS 16384
#define N_CODES 8192
#define DDIM    512
#define NCHUNK  512          // packed f32 slots per row; each = 2 x f16 minima
                             // of 8-code chunks -> 1024 chunks of 8 codes
#define MARGIN  2.5f         // bf16-coarse budget 1.5 (validated R9) + 2*delta
                             // f16-pack quantization (delta ~0.4) -> 2.3 -> 2.5

typedef unsigned int u32;
typedef unsigned long long u64;
typedef unsigned short u16;
typedef __attribute__((ext_vector_type(8))) short short8;   // 8 bf16 = 4 VGPRs
typedef __attribute__((ext_vector_type(4))) float f32x4;

__device__ __forceinline__ u32 float_to_ordered(float f) {
    u32 u = __float_as_uint(f);
    return (u & 0x80000000u) ? ~u : (u | 0x80000000u);
}

__device__ __forceinline__ u16 bf16_rne(float x) {
    u32 u = __float_as_uint(x);
    u32 r = u + 0x7FFFu + ((u >> 16) & 1u);
    return (u16)(r >> 16);
}

__device__ __forceinline__ void gl_lds16(const void* g, void* l) {
    __builtin_amdgcn_global_load_lds((const __attribute__((address_space(1))) u32*)g,
                                     (__attribute__((address_space(3))) u32*)l,
                                     16, 0, 0);
}

__device__ __forceinline__ u64 umin64(u64 a, u64 b) { return a < b ? a : b; }

__device__ __forceinline__ float f16lo(u32 w) {
    return __half2float(__ushort_as_half((unsigned short)(w & 0xFFFFu)));
}
__device__ __forceinline__ float f16hi(u32 w) {
    return __half2float(__ushort_as_half((unsigned short)(w >> 16)));
}

// DPP lane-permute within quads (VALU pipe, avoids ds_bpermute).
// 0xB1 = quad_perm [1,0,3,2] = xor 1;  0x4E = quad_perm [2,3,0,1] = xor 2.
#if __has_builtin(__builtin_amdgcn_update_dpp)
template <int CTRL>
__device__ __forceinline__ float dpp_mov(float x) {
    return __int_as_float(__builtin_amdgcn_update_dpp(
        __float_as_int(x), __float_as_int(x), CTRL, 0xF, 0xF, true));
}
#else
template <int CTRL>
__device__ __forceinline__ float dpp_mov(float x) {
    return __shfl_xor(x, CTRL == 0xB1 ? 1 : 2, 64);
}
#endif

// ---------------------------------------------------------------------------
// Kernel 1: prep (R4-exact).
// ---------------------------------------------------------------------------
__global__ __launch_bounds__(256) void vq_prep(
    const float4* __restrict__ z4, ushort4* __restrict__ zh,
    const float* __restrict__ emb, ushort4* __restrict__ eh,
    float* __restrict__ e_norms) {
    int b = blockIdx.x;
    if (b < (M_ROWS * DDIM) / 1024) {
        int i = b * 256 + threadIdx.x;
        float4 v = z4[i];
        ushort4 h;
        h.x = bf16_rne(v.x); h.y = bf16_rne(v.y);
        h.z = bf16_rne(v.z); h.w = bf16_rne(v.w);
        zh[i] = h;
    } else {
        int wave = threadIdx.x >> 6;
        int lane = threadIdx.x & 63;
        int code = (b - (M_ROWS * DDIM) / 1024) * 4 + wave;
        const float4* ep = (const float4*)(emb + (size_t)code * DDIM);
        size_t base4 = (size_t)code * (DDIM / 4);
        float s = 0.f;
        #pragma unroll
        for (int j = 0; j < 2; ++j) {
            int c = lane + 64 * j;
            float4 e = ep[c];
            s += e.x * e.x + e.y * e.y + e.z * e.z + e.w * e.w;
            ushort4 h;
            h.x = bf16_rne(e.x); h.y = bf16_rne(e.y);
            h.z = bf16_rne(e.z); h.w = bf16_rne(e.w);
            eh[base4 + c] = h;
        }
        #pragma unroll
        for (int off = 32; off; off >>= 1) s += __shfl_down(s, off, 64);
        if (lane == 0) e_norms[code] = s;
    }
}

// ---------------------------------------------------------------------------
// Kernel 2: phase-1 coarse GEMM — R4/R8-EXACT main loop, grid (64,32)
// x-major, ONE tile per block. This grid is L2-CAPACITY-CRITICAL: each
// XCD's 32 co-resident blocks = 8 row-tiles x 4 col-panels = 2 MB A +
// 2 MB B = exactly the 4 MB XCD L2. Every remapping (R5/R7/R9) broke
// this budget and regressed 1.7-2x. DO NOT change block->work mapping.
// Epilogue (changed this round): fold lane bits {2,1,0} only -> two
// 8-code minima per 16-col tile, packed 2xf16 into one f32 slot.
// ---------------------------------------------------------------------------
__device__ __forceinline__ void stage_tile(const char* gbase, int kt,
                                           void* lds, int tid) {
    #pragma unroll
    for (int s = 0; s < 4; ++s) {
        const int row_l = (s << 6) + (tid >> 3);
        const int cb = (((tid & 7) ^ (row_l & 7)) << 4);
        const char* g = gbase + (size_t)row_l * (DDIM * 2) + ((size_t)kt << 7) + cb;
        char* l = (char*)lds + (s << 13) + (tid << 4);
        gl_lds16(g, l);
    }
}

#define BAR() __builtin_amdgcn_s_barrier()
#define LGK0() do { asm volatile("s_waitcnt lgkmcnt(0)" ::: "memory"); \
                    __builtin_amdgcn_sched_barrier(0); } while (0)
#define VMC8() do { asm volatile("s_waitcnt vmcnt(8)" ::: "memory"); } while (0)
#define VMC0() do { asm volatile("s_waitcnt vmcnt(0)" ::: "memory"); } while (0)

#define LDA(BUF, MH) do {                                                      \
    _Pragma("unroll") for (int i_ = 0; i_ < 4; ++i_) {                         \
        _Pragma("unroll") for (int kk_ = 0; kk_ < 2; ++kk_) {                  \
            const int row_ = (wm << 7) + ((((MH) << 2) + i_) << 4) + fr;       \
            const int cb_ = (kk_ << 6) + fkb;                                  \
            a[i_][kk_] = *(const short8*)((const char*)&ldsA[BUF][0][0]        \
                + row_ * 128 + (cb_ ^ ((row_ & 7) << 4)));                     \
        } } } while (0)

#define LDB(BUF, NH) do {                                                      \
    _Pragma("unroll") for (int j_ = 0; j_ < 2; ++j_) {                         \
        _Pragma("unroll") for (int kk_ = 0; kk_ < 2; ++kk_) {                  \
            const int row_ = (wn << 6) + ((((NH) << 1) + j_) << 4) + fr;       \
            const int cb_ = (kk_ << 6) + fkb;                                  \
            b[(NH) * 2 + j_][kk_] = *(const short8*)((const char*)&ldsB[BUF][0][0] \
                + row_ * 128 + (cb_ ^ ((row_ & 7) << 4)));                     \
        } } } while (0)

#define MFMA_Q(MH, NH) do {                                                    \
    __builtin_amdgcn_s_setprio(1);                                             \
    _Pragma("unroll") for (int i_ = 0; i_ < 4; ++i_) {                         \
        _Pragma("unroll") for (int j_ = 0; j_ < 2; ++j_) {                     \
            _Pragma("unroll") for (int kk_ = 0; kk_ < 2; ++kk_) {              \
                acc[(MH) * 4 + i_][(NH) * 2 + j_] =                            \
                    __builtin_amdgcn_mfma_f32_16x16x32_bf16(                   \
                        a[i_][kk_], b[(NH) * 2 + j_][kk_],                     \
                        acc[(MH) * 4 + i_][(NH) * 2 + j_], 0, 0, 0);           \
        } } }                                                                  \
    __builtin_amdgcn_s_setprio(0);                                             \
} while (0)

#define PH_ITER(SE, VMA, VMB, NK0, NK1)                                        \
    LDA(0, 0); LDB(0, 0);                                                      \
    BAR(); LGK0(); MFMA_Q(0, 0); BAR();                                        \
    LDB(0, 1);                                                                 \
    BAR(); LGK0(); MFMA_Q(0, 1); BAR();                                        \
    LDA(0, 1);                                                                 \
    if (SE) stage_tile(gB0, (NK0), &ldsB[0][0][0], tid);                       \
    BAR(); LGK0(); MFMA_Q(1, 0); BAR();                                        \
    if (SE) stage_tile(gA0, (NK0), &ldsA[0][0][0], tid);                       \
    BAR(); MFMA_Q(1, 1); VMA; BAR();                                           \
    LDA(1, 0); LDB(1, 0);                                                      \
    BAR(); LGK0(); MFMA_Q(0, 0); BAR();                                        \
    LDB(1, 1);                                                                 \
    BAR(); LGK0(); MFMA_Q(0, 1); BAR();                                        \
    LDA(1, 1);                                                                 \
    if (SE) stage_tile(gB0, (NK1), &ldsB[1][0][0], tid);                       \
    BAR(); LGK0(); MFMA_Q(1, 0); BAR();                                        \
    if (SE) stage_tile(gA0, (NK1), &ldsA[1][0][0], tid);                       \
    BAR(); MFMA_Q(1, 1); VMB; BAR();

__global__ __launch_bounds__(512, 2) void vq_phase1(
    const u16* __restrict__ z_hi, const u16* __restrict__ e_hi,
    const float* __restrict__ e_norms,
    float* __restrict__ chunkmin) {
    __shared__ __align__(16) u16 ldsA[2][256][64];   // 64 KB
    __shared__ __align__(16) u16 ldsB[2][256][64];   // 64 KB

    const int tid  = threadIdx.x;
    const int lane = tid & 63;
    const int wid  = tid >> 6;
    const int wm   = wid >> 2;          // 0..1
    const int wn   = wid & 3;           // 0..3
    const int row0 = blockIdx.x << 8;
    const int col0 = blockIdx.y << 8;
    const int fr   = lane & 15;
    const int fkb  = (lane >> 4) << 4;  // k byte offset within 32-elem slice

    const char* gA0 = (const char*)z_hi + (size_t)row0 * (DDIM * 2);
    const char* gB0 = (const char*)e_hi + (size_t)col0 * (DDIM * 2);

    f32x4 acc[8][4] = {};
    short8 a[4][2], b[4][2];

    // prologue: stage K-tiles 0 (buf0) and 1 (buf1)
    stage_tile(gA0, 0, &ldsA[0][0][0], tid);
    stage_tile(gB0, 0, &ldsB[0][0][0], tid);
    stage_tile(gA0, 1, &ldsA[1][0][0], tid);
    stage_tile(gB0, 1, &ldsB[1][0][0], tid);
    VMC8(); BAR();

    #pragma unroll 1
    for (int t = 0; t < 3; ++t) {
        const int nk0 = 2 * t + 2, nk1 = 2 * t + 3;
        PH_ITER(1, VMC8(), VMC8(), nk0, nk1)
    }
    // drain iteration: no stages; vmcnt(0) before buf1 phases.
    PH_ITER(0, VMC0(), ((void)0), 0, 0)

    // epilogue: C layout col = lane&15, row = (lane>>4)*4 + reg.
    // Fold lane bits {2,1,0} only: each lane ends with the min over its
    // 8-col half (bit3 = half) of its owned j-tile (j = 2*bit2 + bit1).
    // Pack lo/hi halves as 2xf16 into one f32 slot (lane cn&9 == 0 writes).
    const int cn = lane & 15;
    const int cg = lane >> 4;
    float en[4];
    #pragma unroll
    for (int j = 0; j < 4; ++j) en[j] = e_norms[col0 + (wn << 6) + j * 16 + cn];

    #pragma unroll
    for (int i = 0; i < 8; ++i)
        #pragma unroll
        for (int r = 0; r < 4; ++r) {
            float mv[4];
            #pragma unroll
            for (int j = 0; j < 4; ++j) mv[j] = en[j] - 2.0f * acc[i][j][r];

            // fold lane bit2: regs 4->2 (ownership bit2)
            #pragma unroll
            for (int k = 0; k < 2; ++k) {
                float lo = mv[k], hi = mv[k + 2];
                float mine = (lane & 4) ? hi : lo;
                float thrs = (lane & 4) ? lo : hi;
                mv[k] = fminf(mine, __shfl_xor(thrs, 4, 64));
            }
            // fold lane bit1: regs 2->1 (ownership bit1)
            {
                float lo = mv[0], hi = mv[1];
                float mine = (lane & 2) ? hi : lo;
                float thrs = (lane & 2) ? lo : hi;
                mv[0] = fminf(mine, __shfl_xor(thrs, 2, 64));
            }
            // fold lane bit0 (broadcast min within pairs)
            mv[0] = fminf(mv[0], dpp_mov<0xB1>(mv[0]));
            // partner lane (cn^8) holds the other 8-col half of the same j
            float other = __shfl_xor(mv[0], 8, 64);

            if ((cn & 9) == 0) {   // cn in {0,2,4,6}: bit3=0 (lo half), bit0=0
                const int jj = (((cn >> 2) & 1) << 1) | ((cn >> 1) & 1);
                u32 plo = (u32)__half_as_ushort(__float2half(mv[0]));
                u32 phi = (u32)__half_as_ushort(__float2half(other));
                const int row_g = row0 + (wm << 7) + (i << 4) + (cg << 2) + r;
                chunkmin[(size_t)row_g * NCHUNK + (col0 >> 4) + (wn << 2) + jj] =
                    __uint_as_float(plo | (phi << 16));
            }
        }
}

// ---------------------------------------------------------------------------
// Kernel 3a: threshold + candidate masks. One wave per row.
// Unpacks 1024 f16 8-code-chunk minima (512 packed slots), computes
// thr = min + MARGIN, ballots 16 mask words (mask k bit l <-> slot
// (k>>3)*256 + 4*l + ((k>>1)&3), half k&1), lane0 writes them IN-PLACE
// into the row prefix (128 B). Minima fully consumed before overwrite.
// ---------------------------------------------------------------------------
__global__ __launch_bounds__(256) void vq_fin_a(
    float* __restrict__ chunkmin) {
    const int wave = threadIdx.x >> 6;
    const int lane = threadIdx.x & 63;
    const int row  = blockIdx.x * 4 + wave;

    float* cmrow = chunkmin + (size_t)row * NCHUNK;
    const float4* cm4 = (const float4*)cmrow;
    float4 v0 = cm4[lane];
    float4 v1 = cm4[64 + lane];

    u32 w[8];
    w[0] = __float_as_uint(v0.x); w[1] = __float_as_uint(v0.y);
    w[2] = __float_as_uint(v0.z); w[3] = __float_as_uint(v0.w);
    w[4] = __float_as_uint(v1.x); w[5] = __float_as_uint(v1.y);
    w[6] = __float_as_uint(v1.z); w[7] = __float_as_uint(v1.w);

    float vals[16];
    #pragma unroll
    for (int i = 0; i < 8; ++i) { vals[2 * i] = f16lo(w[i]); vals[2 * i + 1] = f16hi(w[i]); }

    float m = vals[0];
    #pragma unroll
    for (int i = 1; i < 16; ++i) m = fminf(m, vals[i]);
    #pragma unroll
    for (int off = 1; off < 64; off <<= 1) m = fminf(m, __shfl_xor(m, off, 64));
    const float thr = m + MARGIN;

    u64 msk[16];
    #pragma unroll
    for (int k = 0; k < 16; ++k) msk[k] = __ballot(vals[k] <= thr);

    if (lane == 0) {
        u64* mrow = (u64*)cmrow;
        #pragma unroll
        for (int i = 0; i < 16; ++i) mrow[i] = msk[i];
    }
}

// ---------------------------------------------------------------------------
// Kernel 3b: exact re-eval + winner gather, 8-CODE chunks (16 KB/chunk,
// half of R10). Reads 16 mask words (128 B/row), evaluates candidate
// chunks in exact fp32 (reduce-scatter butterfly over 8 regs: 10 cross-
// lane ops; lane owns code ((l&1)<<2)|(l&2)|((l>>2)&1)), wave argmin,
// gather, outputs, loss partial. NO fences (R7: per-block fence flushed
// L2, 3x regression). chunkmin row overwritten by out_q at end.
// ---------------------------------------------------------------------------
__global__ __launch_bounds__(256) void vq_fin_b(
    const float* __restrict__ z, const float* __restrict__ emb,
    const float* __restrict__ e_norms, const float* __restrict__ chunkmin,
    float* __restrict__ out_q, float* __restrict__ out_idx,
    float* __restrict__ partials) {
    const int wave = threadIdx.x >> 6;
    const int lane = threadIdx.x & 63;
    const int row  = blockIdx.x * 4 + wave;

    const u64* mrow = (const u64*)(chunkmin + (size_t)row * NCHUNK);
    u64 msk[16];
    #pragma unroll
    for (int i = 0; i < 16; ++i) msk[i] = mrow[i];

    const float4* z4 = (const float4*)(z + (size_t)row * DDIM);
    float4 za = z4[2 * lane];
    float4 zb = z4[2 * lane + 1];

    // code owned after reduce-scatter: bits folded (0,1,2) -> code (2,1,0)
    const int cown = ((lane & 1) << 2) | (lane & 2) | ((lane >> 2) & 1);

    u64 best = 0xFFFFFFFFFFFFFFFFull;
    #pragma unroll
    for (int wnd = 0; wnd < 16; ++wnd) {
        const int p = wnd >> 3;            // v0/v1 half of the row
        const int c = (wnd >> 1) & 3;      // float4 component
        const int h = wnd & 1;             // lo/hi f16 half
        u64 mk = msk[wnd];
        while (mk) {
            int l = __ffsll((long long)mk) - 1;
            mk &= mk - 1;
            const int slot  = (p << 8) + (l << 2) + c;   // packed f32 slot
            const int cbase = ((slot << 1) + h) << 3;    // 8 codes/chunk
            const float* eb = emb + (size_t)cbase * DDIM + lane * 8;
            float part[8];
            #pragma unroll
            for (int k = 0; k < 8; ++k) {
                float4 ea = *(const float4*)(eb + (size_t)k * DDIM);
                float4 e2 = *(const float4*)(eb + (size_t)k * DDIM + 4);
                part[k] = za.x * ea.x + za.y * ea.y + za.z * ea.z + za.w * ea.w
                        + zb.x * e2.x + zb.y * e2.y + zb.z * e2.z + zb.w * e2.w;
            }
            // reduce-scatter butterfly: fold lane bits 0,1,2; then replicas.
            #pragma unroll
            for (int k = 0; k < 4; ++k) {            // xor1 (DPP)
                float lo = part[k], hi = part[k + 4];
                float mine = (lane & 1) ? hi : lo;
                float thrs = (lane & 1) ? lo : hi;
                part[k] = mine + dpp_mov<0xB1>(thrs);
            }
            #pragma unroll
            for (int k = 0; k < 2; ++k) {            // xor2 (DPP)
                float lo = part[k], hi = part[k + 2];
                float mine = (lane & 2) ? hi : lo;
                float thrs = (lane & 2) ? lo : hi;
                part[k] = mine + dpp_mov<0x4E>(thrs);
            }
            {                                         // xor4
                float lo = part[0], hi = part[1];
                float mine = (lane & 4) ? hi : lo;
                float thrs = (lane & 4) ? lo : hi;
                part[0] = mine + __shfl_xor(thrs, 4, 64);
            }
            part[0] += __shfl_xor(part[0], 8, 64);    // replica sums
            part[0] += __shfl_xor(part[0], 16, 64);
            part[0] += __shfl_xor(part[0], 32, 64);

            const int ci = cbase + cown;
            float dist = e_norms[ci] - 2.0f * part[0];
            best = umin64(best, ((u64)float_to_ordered(dist) << 32) | (u32)ci);
        }
    }

    #pragma unroll
    for (int off = 1; off < 64; off <<= 1)
        best = umin64(best, __shfl_xor(best, off, 64));

    const int idx = (int)(best & 0xFFFFFFFFull);
    const float* ew = emb + (size_t)idx * DDIM + lane * 8;
    float4 qa = *(const float4*)ew;
    float4 qb = *(const float4*)(ew + 4);
    float4* op = (float4*)(out_q + (size_t)row * DDIM);
    op[2 * lane]     = qa;
    op[2 * lane + 1] = qb;

    float dx, local = 0.f;
    dx = za.x - qa.x; local += dx * dx;  dx = za.y - qa.y; local += dx * dx;
    dx = za.z - qa.z; local += dx * dx;  dx = za.w - qa.w; local += dx * dx;
    dx = zb.x - qb.x; local += dx * dx;  dx = zb.y - qb.y; local += dx * dx;
    dx = zb.z - qb.z; local += dx * dx;  dx = zb.w - qb.w; local += dx * dx;
    #pragma unroll
    for (int off = 32; off; off >>= 1) local += __shfl_down(local, off, 64);

    __shared__ float wsum[4];
    if (lane == 0) { wsum[wave] = local; out_idx[row] = (float)idx; }
    __syncthreads();
    if (threadIdx.x == 0)
        partials[blockIdx.x] = wsum[0] + wsum[1] + wsum[2] + wsum[3];
}

// ---------------------------------------------------------------------------
// Kernel 4: reduce 4096 loss partials -> scalar loss. Own tiny dispatch
// (R7: fence-based fusion flushed L2, 3x fin_b regression).
// ---------------------------------------------------------------------------
__global__ __launch_bounds__(256) void vq_loss_reduce(
    const float* __restrict__ partials, float* __restrict__ out_loss) {
    __shared__ float red[256];
    float s = 0.f;
    for (int i = threadIdx.x; i < M_ROWS / 4; i += 256) s += partials[i];
    red[threadIdx.x] = s;
    __syncthreads();
    for (int off = 128; off; off >>= 1) {
        if (threadIdx.x < off) red[threadIdx.x] += red[threadIdx.x + off];
        __syncthreads();
    }
    if (threadIdx.x == 0)
        out_loss[0] = 0.25f * red[0] / ((float)M_ROWS * (float)DDIM);
}

extern "C" void kernel_launch(void* const* d_in, const int* in_sizes, int n_in,
                              void* d_out, int out_size, void* d_ws, size_t ws_size,
                              hipStream_t stream) {
    (void)in_sizes; (void)n_in; (void)out_size; (void)ws_size;
    const float* z   = (const float*)d_in[0];   // [16384, 512]
    const float* emb = (const float*)d_in[1];   // [8192, 512]

    float* out      = (float*)d_out;
    float* out_q    = out;
    float* out_idx  = out + (size_t)M_ROWS * DDIM;
    float* out_loss = out + (size_t)M_ROWS * DDIM + M_ROWS;

    // ws layout (requires ws_size >= 49152 + 24 MB):
    //   [0,32K) e_norms | [32K,48K) partials | [48K,+16MB) z_hi | +8MB e_hi
    char* ws = (char*)d_ws;
    float* e_norms  = (float*)ws;
    float* partials = (float*)(ws + 32768);
    u16* z_hi = (u16*)(ws + 49152);
    u16* e_hi = (u16*)(ws + 49152 + (size_t)M_ROWS * DDIM * 2);

    // chunkmin [16384][512] f32 (packed 2xf16/slot) = 32 MB aliases out_q
    // EXACTLY (2048 B/row). phase1 fills it; fin_a consumes each row then
    // overwrites its 128 B prefix with 16 candidate-mask words; fin_b reads
    // the masks, then overwrites the row with out_q. Stream-ordered,
    // wave-private rows -> race-free.
    float* chunkmin = out_q;

    const int zblocks = (M_ROWS * DDIM) / 1024;      // 16384
    const int eblocks = N_CODES / 4;                 // 2048
    vq_prep<<<zblocks + eblocks, 256, 0, stream>>>(
        (const float4*)z, (ushort4*)z_hi, emb, (ushort4*)e_hi, e_norms);

    vq_phase1<<<dim3(M_ROWS / 256, N_CODES / 256), 512, 0, stream>>>(
        z_hi, e_hi, e_norms, chunkmin);

    vq_fin_a<<<M_ROWS / 4, 256, 0, stream>>>(chunkmin);

    vq_fin_b<<<M_ROWS / 4, 256, 0, stream>>>(
        z, emb, e_norms, chunkmin, out_q, out_idx, partials);

    vq_loss_reduce<<<1, 256, 0, stream>>>(partials, out_loss);
}